// Round 16
// baseline (132.201 us; speedup 1.0000x reference)
//
#include <hip/hip_runtime.h>
#include <hip/hip_fp16.h>

typedef __attribute__((ext_vector_type(8))) short short8;
typedef __attribute__((ext_vector_type(4))) float f32x4;

constexpr int D_OUTC = 128;
constexpr int T_LEN  = 512;
constexpr int C_INC  = 2;
constexpr int F_BINS = 1025;
constexpr int N_BANDS= 128;
constexpr int MAX_W  = 80;
constexpr int SCAP   = 4224;
constexpr int ZSTRU  = 136;    // z row stride in ushorts (272B = 17x16B, bank-rotating)

__device__ inline unsigned short bf16r(float f) {
  unsigned u = __float_as_uint(f);
  unsigned r = u + 0x7FFFu + ((u >> 16) & 1u);
  return (unsigned short)(r >> 16);
}
// RNE convert f32[8] -> bf16x8
__device__ inline short8 cvt8(const float v[8]) {
  short8 h;
  #pragma unroll
  for (int j = 0; j < 8; ++j) h[j] = (short)bf16r(v[j]);
  return h;
}

// ============ meta A: per-band len/start (parallel; R14 lesson: never single-block) ============
__global__ void k_len(const float* __restrict__ mask, const int* __restrict__ idx, int W,
                      int* __restrict__ lenT, int* __restrict__ startT) {
  const int k = blockIdx.x;
  const int lane = threadIdx.x;
  int cnt = 0;
  for (int w = lane; w < W; w += 64) cnt += (mask[k * W + w] != 0.f) ? 1 : 0;
  #pragma unroll
  for (int s = 32; s > 0; s >>= 1) cnt += __shfl_xor(cnt, s, 64);
  if (lane == 0) { lenT[k] = cnt; startT[k] = idx[k * W]; }
}
// ============ meta B: lenP + scan + LPT permutation ============
__global__ void k_scan(const int* __restrict__ lenT, int* __restrict__ lenPT,
                       int* __restrict__ offT, int* __restrict__ permT) {
  const int k = threadIdx.x;
  int l = lenT[k];
  lenPT[k] = (l + 15) & ~15;
  __shared__ int sh[N_BANDS];
  __shared__ int sl[N_BANDS];
  sh[k] = 2 * l;
  sl[k] = l;
  __syncthreads();
  for (int s = 1; s < N_BANDS; s <<= 1) {
    int t = (k >= s) ? sh[k - s] : 0;
    __syncthreads();
    sh[k] += t;
    __syncthreads();
  }
  offT[k] = sh[k] - 2 * l;
  if (k == N_BANDS - 1) offT[N_BANDS] = sh[k];
  int rank = 0;
  for (int j = 0; j < N_BANDS; ++j)
    rank += (sl[j] > l) || (sl[j] == l && j < k);
  permT[rank] = k;
}
// ============ meta C: inverse map, grid over f ============
__global__ void k_inv2(const int* __restrict__ startT, const int* __restrict__ lenT,
                       const int* __restrict__ offT, int* __restrict__ inv) {
  int f = blockIdx.x * 256 + threadIdx.x;
  if (f >= F_BINS) return;
  int r0 = -1, r1 = -1, r2 = -1, r3 = -1;
  int n = 0;
  for (int k = 0; k < N_BANDS; ++k) {
    unsigned rel = (unsigned)(f - startT[k]);
    if (rel < (unsigned)lenT[k]) {
      int v = offT[k] + 2 * (int)rel;
      if (n == 0) r0 = v; else if (n == 1) r1 = v; else if (n == 2) r2 = v; else r3 = v;
      ++n;
    }
  }
  *(int4*)&inv[f * 4] = make_int4(r0, r1, r2, r3);
}

// ============ W1' prep: fold mel*mask, planar i' = w + c*lenP, bf16-hi (RNE) ============
__global__ void prep_w1(const float* __restrict__ pre_w, const float* __restrict__ mel,
                        const float* __restrict__ mask, const int* __restrict__ lenPT,
                        unsigned short* __restrict__ hh,
                        int W, int i1, int K1PA) {
  const int band = blockIdx.y;
  const int ip = blockIdx.x * 32 + (threadIdx.x & 31);
  const int lp = lenPT[band];
  const int c  = (ip >= lp) ? 1 : 0;
  const int w  = ip - (c ? lp : 0);
  const bool live = (ip < 2 * lp) && (w < W);
  float s = 0.f; int row = 0;
  if (live) { s = mel[band * W + w] * mask[band * W + w]; row = 2 * w + c; }
  for (int d = (threadIdx.x >> 5); d < D_OUTC; d += 8) {
    float v = live ? s * pre_w[((size_t)band * i1 + row) * D_OUTC + d] : 0.f;
    hh[((size_t)(band * D_OUTC + d)) * K1PA + ip] = bf16r(v);
  }
}

// ============ W2' prep: fold mask/ola, bf16-hi (RNE); also emits postbS ============
__global__ void prep_w2(const float* __restrict__ post_w, const float* __restrict__ post_b,
                        const float* __restrict__ mask,
                        const int* __restrict__ idx, const float* __restrict__ ola,
                        unsigned short* __restrict__ hh, float* __restrict__ postbS,
                        int W, int i1, int K1PA) {
  const int band = blockIdx.y;
  const int o  = blockIdx.x * 2 + (threadIdx.x >> 7);
  const int dd = threadIdx.x & 127;
  float s = 0.f;
  if (o < i1) {
    int w = o >> 1;
    float mk = mask[band * W + w];
    if (mk != 0.f) s = mk / ola[idx[band * W + w]];
  }
  float v = (o < i1) ? s * post_w[((size_t)band * D_OUTC + dd) * i1 + o] : 0.f;
  hh[((size_t)(band * K1PA + o)) * D_OUTC + dd] = bf16r(v);
  if (dd == 0 && o < i1)
    postbS[band * i1 + o] = s * post_b[band * i1 + o];
}

// ============ main: 64-row blocks, 2 waves x 32 rows; GEMM1 in two d-half passes ============
// R16 occupancy round: acc shrinks 64->32 regs (two d-passes, x re-read L1-hot);
// z stored bf16 in LDS at write time (same RNE numerics); GEMM2 streams z from
// LDS (no persistent z regs, no ot-pairing). Target 5 waves/SIMD.
__global__ __launch_bounds__(128, 5)
void bandsplit_main(const float* __restrict__ x,
                    const unsigned short* __restrict__ wB1h,
                    const unsigned short* __restrict__ wB2h,
                    const float* __restrict__ pre_b,
                    const float* __restrict__ postbS,
                    const int* __restrict__ lenT,
                    const int* __restrict__ lenPT,
                    const int* __restrict__ offT,
                    const int* __restrict__ startT,
                    const int* __restrict__ permT,
                    __half* __restrict__ y,
                    int i1, int K1PA, int nmt)
{
  const int bid  = blockIdx.x;
  const int band = permT[bid / nmt];         // LPT: heavy bands first
  const int mt   = bid - (bid / nmt) * nmt;

  const int lenv = lenT[band];
  if (lenv == 0) return;
  const int lp   = lenPT[band];
  const int nks  = lp >> 4;
  const int i1e  = 2 * lenv;
  const int nOT  = (i1e + 15) >> 4;
  const int offk = offT[band];
  const int strt = startT[band];

  const int mbase = mt * 64;
  const int b  = mbase >> 9;                 // 64 | 512
  const int t0 = mbase & 511;
  const int tid  = threadIdx.x;
  const int lane = tid & 63;
  const int wid  = tid >> 6;                 // 0..1
  const int lr = lane & 15, lk = lane >> 4;
  const int m0 = wid * 32;

  __shared__ unsigned short zAll[2][32 * ZSTRU];   // bf16 z, both 16-row halves live
  unsigned short* zw = zAll[wid];

  const float* xr0A = x + ((size_t)(b * C_INC) * T_LEN + (t0 + m0 + lr)) * F_BINS + strt;
  const float* xr0B = xr0A + (size_t)16 * F_BINS;
  const size_t xcs = (size_t)T_LEN * F_BINS;

  // ---- GEMM1: two d-half passes; per pass acc = 32 regs; B-loads shared A/B ----
  #pragma unroll
  for (int dpass = 0; dpass < 2; ++dpass) {
    f32x4 aA[4] = {}, aB[4] = {};
    const unsigned short* b1p = wB1h + ((size_t)(band * D_OUTC + dpass * 64) + lr) * K1PA;

    for (int ks = 0; ks < nks; ++ks) {
      const int i0 = ks * 32 + lk * 8;
      const int cs = (i0 >= lp) ? 1 : 0;
      const int w0 = i0 - (cs ? lp : 0);
      const float* xrA = xr0A + (cs ? xcs : 0) + w0;
      const float* xrB = xr0B + (cs ? xcs : 0) + w0;
      float xvA[8], xvB[8];
      if (w0 + 8 <= lenv) {
        float4 q0, q1, q2, q3;
        __builtin_memcpy(&q0, xrA,     16);
        __builtin_memcpy(&q1, xrA + 4, 16);
        __builtin_memcpy(&q2, xrB,     16);
        __builtin_memcpy(&q3, xrB + 4, 16);
        xvA[0]=q0.x; xvA[1]=q0.y; xvA[2]=q0.z; xvA[3]=q0.w;
        xvA[4]=q1.x; xvA[5]=q1.y; xvA[6]=q1.z; xvA[7]=q1.w;
        xvB[0]=q2.x; xvB[1]=q2.y; xvB[2]=q2.z; xvB[3]=q2.w;
        xvB[4]=q3.x; xvB[5]=q3.y; xvB[6]=q3.z; xvB[7]=q3.w;
      } else {
        #pragma unroll
        for (int j = 0; j < 8; ++j) {
          bool ok = (w0 + j < lenv);
          xvA[j] = ok ? xrA[j] : 0.f;
          xvB[j] = ok ? xrB[j] : 0.f;
        }
      }
      const short8 ahA = cvt8(xvA);
      const short8 ahB = cvt8(xvB);

      short8 BH[4];
      #pragma unroll
      for (int t = 0; t < 4; ++t)
        BH[t] = *(const short8*)&b1p[(size_t)t * 16 * K1PA + i0];
      #pragma unroll
      for (int t = 0; t < 4; ++t) {
        aA[t] = __builtin_amdgcn_mfma_f32_16x16x32_bf16(ahA, BH[t], aA[t], 0, 0, 0);
        aB[t] = __builtin_amdgcn_mfma_f32_16x16x32_bf16(ahB, BH[t], aB[t], 0, 0, 0);
      }
    }

    // write this d-half (+bias) as bf16 into LDS; C layout: col=lr, row=lk*4+r
    #pragma unroll
    for (int t = 0; t < 4; ++t) {
      const int d = dpass * 64 + t * 16 + lr;
      const float pb = pre_b[band * D_OUTC + d];
      #pragma unroll
      for (int r = 0; r < 4; ++r) {
        const int m = lk * 4 + r;
        zw[m * ZSTRU + d]        = bf16r(aA[t][r] + pb);
        zw[(16 + m) * ZSTRU + d] = bf16r(aB[t][r] + pb);
      }
    }
  }

  // Fence: cross-lane LDS write->read dependency (R4 race lesson). Do NOT remove.
  __syncthreads();

  // ---- GEMM2: stream z A-frags from LDS; store y (fp16, pre-scaled) ----
  const unsigned short* b2h = wB2h + ((size_t)(band * K1PA) + lr) * D_OUTC;
  for (int ot = 0; ot < nOT; ++ot) {
    short8 B0[4];
    #pragma unroll
    for (int ks = 0; ks < 4; ++ks)
      B0[ks] = *(const short8*)&b2h[(size_t)ot * 16 * D_OUTC + ks * 32 + lk * 8];
    f32x4 aA = {}, aB = {};
    #pragma unroll
    for (int ks = 0; ks < 4; ++ks) {
      const short8 zA = *(const short8*)&zw[lr * ZSTRU + ks * 32 + lk * 8];
      const short8 zB = *(const short8*)&zw[(16 + lr) * ZSTRU + ks * 32 + lk * 8];
      aA = __builtin_amdgcn_mfma_f32_16x16x32_bf16(zA, B0[ks], aA, 0, 0, 0);
      aB = __builtin_amdgcn_mfma_f32_16x16x32_bf16(zB, B0[ks], aB, 0, 0, 0);
    }
    const int o = ot * 16 + lr;
    if (o < i1e) {
      const float pb = postbS[band * i1 + o];
      const size_t ybA = ((size_t)(b * T_LEN + t0 + m0 + lk * 4)) * SCAP + offk + o;
      const size_t ybB = ybA + (size_t)16 * SCAP;
      #pragma unroll
      for (int r = 0; r < 4; ++r) {
        y[ybA + (size_t)r * SCAP] = __float2half_rn(aA[r] + pb);
        y[ybB + (size_t)r * SCAP] = __float2half_rn(aB[r] + pb);
      }
    }
  }
}

// ============ merge: half2 loads cover both channels; two coalesced row stores ============
__global__ __launch_bounds__(256, 8)
void k_merge(const __half* __restrict__ y, const int* __restrict__ inv,
             float* __restrict__ out, int nbt) {
  const size_t crow = (size_t)T_LEN * F_BINS;
  for (int row = blockIdx.x; row < nbt; row += gridDim.x) {   // row = b*T + t
    const int t = row & 511;
    const int b = row >> 9;
    const size_t ybase = (size_t)row * SCAP;
    float* o0 = out + ((size_t)(b * C_INC) * T_LEN + t) * F_BINS;
    float* o1 = o0 + crow;
    for (int f = threadIdx.x; f < F_BINS; f += 256) {
      const int4 iv = *reinterpret_cast<const int4*>(&inv[f * 4]);
      float s0 = 0.f, s1 = 0.f;
      if (iv.x >= 0) {
        const __half2 h = *reinterpret_cast<const __half2*>(&y[ybase + iv.x]);
        s0 += __half2float(h.x); s1 += __half2float(h.y);
      }
      if (iv.y >= 0) {
        const __half2 h = *reinterpret_cast<const __half2*>(&y[ybase + iv.y]);
        s0 += __half2float(h.x); s1 += __half2float(h.y);
      }
      if (iv.z >= 0) {
        const __half2 h = *reinterpret_cast<const __half2*>(&y[ybase + iv.z]);
        s0 += __half2float(h.x); s1 += __half2float(h.y);
      }
      if (iv.w >= 0) {
        const __half2 h = *reinterpret_cast<const __half2*>(&y[ybase + iv.w]);
        s0 += __half2float(h.x); s1 += __half2float(h.y);
      }
      o0[f] = s0;
      o1[f] = s1;
    }
  }
}

// ================= fallback: fp32 fused (atomics) + naive =================
#define TPB 256
constexpr int MT     = 32;
constexpr int MAX_I1 = 2 * MAX_W;
constexpr int MAX_I1P= (MAX_I1 + 31) & ~31;
constexpr int GSTR   = 36;

__global__ __launch_bounds__(TPB, 2)
void bandsplit_fused(const float* __restrict__ x,
                     const float* __restrict__ pre_w,
                     const float* __restrict__ pre_b,
                     const float* __restrict__ post_w,
                     const float* __restrict__ post_b,
                     const float* __restrict__ mel,
                     const float* __restrict__ mask,
                     const float* __restrict__ ola,
                     const int*   __restrict__ idx,
                     float* __restrict__ out,
                     int W)
{
    const int i1  = 2 * W;
    const int I1P = (i1 + 31) & ~31;
    const int k     = blockIdx.y;
    const int mbase = blockIdx.x * MT;
    const int b     = mbase / T_LEN;
    const int t0    = mbase % T_LEN;
    const int tid = threadIdx.x;
    const int td  = tid & 31;
    const int tm  = tid >> 5;

    __shared__ float gT[MAX_I1P * GSTR];
    __shared__ float zT[D_OUTC * GSTR];
    __shared__ float wS[32 * D_OUTC];
    __shared__ float s_preb[D_OUTC];
    __shared__ float s_postb[MAX_I1];
    __shared__ float s_melmask[MAX_W];
    __shared__ float s_mask[MAX_W];
    __shared__ float s_iola[MAX_W];
    __shared__ int   s_idx[MAX_W];

    for (int j = tid; j < W; j += TPB) {
        int   f  = idx[k * W + j];
        float mv = mel[k * W + j];
        float mk = mask[k * W + j];
        s_idx[j]     = f;
        s_melmask[j] = mv * mk;
        s_mask[j]    = mk;
        s_iola[j]    = 1.0f / ola[f];
    }
    for (int j = tid; j < D_OUTC; j += TPB) s_preb[j]  = pre_b[k * D_OUTC + j];
    for (int j = tid; j < i1;     j += TPB) s_postb[j] = post_b[k * i1 + j];
    for (int j = tid; j < I1P * GSTR; j += TPB) gT[j] = 0.f;
    __syncthreads();

    for (int j = tid; j < MT * i1; j += TPB) {
        int w  = j % W;
        int cm = j / W;
        int c  = cm & 1;
        int ml = cm >> 1;
        int f  = s_idx[w];
        float v = x[((b * C_INC + c) * T_LEN + (t0 + ml)) * F_BINS + f] * s_melmask[w];
        gT[(2 * w + c) * GSTR + ml] = v;
    }
    __syncthreads();

    float az[4][4] = {};
    for (int i0 = 0; i0 < I1P; i0 += 32) {
        for (int j = tid; j < 32 * D_OUTC; j += TPB) {
            int ii = j >> 7, d = j & 127;
            int i  = i0 + ii;
            wS[j] = (i < i1) ? pre_w[(k * i1 + i) * D_OUTC + d] : 0.f;
        }
        __syncthreads();
        #pragma unroll 8
        for (int ii = 0; ii < 32; ++ii) {
            const float4 wv = *reinterpret_cast<const float4*>(&wS[ii * D_OUTC + td * 4]);
            const float4 gv = *reinterpret_cast<const float4*>(&gT[(i0 + ii) * GSTR + tm * 4]);
            az[0][0] += gv.x * wv.x; az[0][1] += gv.x * wv.y; az[0][2] += gv.x * wv.z; az[0][3] += gv.x * wv.w;
            az[1][0] += gv.y * wv.x; az[1][1] += gv.y * wv.y; az[1][2] += gv.y * wv.z; az[1][3] += gv.y * wv.w;
            az[2][0] += gv.z * wv.x; az[2][1] += gv.z * wv.y; az[2][2] += gv.z * wv.z; az[2][3] += gv.z * wv.w;
            az[3][0] += gv.w * wv.x; az[3][1] += gv.w * wv.y; az[3][2] += gv.w * wv.z; az[3][3] += gv.w * wv.w;
        }
        __syncthreads();
    }
    #pragma unroll
    for (int jj = 0; jj < 4; ++jj) {
        int d = td * 4 + jj;
        float bb = s_preb[d];
        #pragma unroll
        for (int r = 0; r < 4; ++r)
            zT[d * GSTR + tm * 4 + r] = az[r][jj] + bb;
    }
    __syncthreads();

    const int NOG = (i1 + 127) >> 7;
    for (int og = 0; og < NOG; ++og) {
        float ay[4][4] = {};
        for (int d0 = 0; d0 < D_OUTC; d0 += 32) {
            for (int j = tid; j < 32 * D_OUTC; j += TPB) {
                int dd = j >> 7, oo = j & 127;
                int o  = og * 128 + oo;
                wS[j] = (o < i1) ? post_w[(k * D_OUTC + d0 + dd) * i1 + o] : 0.f;
            }
            __syncthreads();
            #pragma unroll 8
            for (int dd = 0; dd < 32; ++dd) {
                const float4 wv = *reinterpret_cast<const float4*>(&wS[dd * D_OUTC + td * 4]);
                const float4 zv = *reinterpret_cast<const float4*>(&zT[(d0 + dd) * GSTR + tm * 4]);
                ay[0][0] += zv.x * wv.x; ay[0][1] += zv.x * wv.y; ay[0][2] += zv.x * wv.z; ay[0][3] += zv.x * wv.w;
                ay[1][0] += zv.y * wv.x; ay[1][1] += zv.y * wv.y; ay[1][2] += zv.y * wv.z; ay[1][3] += zv.y * wv.w;
                ay[2][0] += zv.z * wv.x; ay[2][1] += zv.z * wv.y; ay[2][2] += zv.z * wv.z; ay[2][3] += zv.z * wv.w;
                ay[3][0] += zv.w * wv.x; ay[3][1] += zv.w * wv.y; ay[3][2] += zv.w * wv.z; ay[3][3] += zv.w * wv.w;
            }
            __syncthreads();
        }
        #pragma unroll
        for (int jj = 0; jj < 4; ++jj) {
            int o = og * 128 + td * 4 + jj;
            if (o < i1) {
                int w = o >> 1, c = o & 1;
                float mk = s_mask[w];
                if (mk != 0.f) {
                    int f = s_idx[w];
                    float scale = mk * s_iola[w];
                    float bb = s_postb[o];
                    #pragma unroll
                    for (int r = 0; r < 4; ++r) {
                        int ml = tm * 4 + r;
                        float val = (ay[r][jj] + bb) * scale;
                        atomicAdd(&out[((b * C_INC + c) * T_LEN + (t0 + ml)) * F_BINS + f], val);
                    }
                }
            }
        }
    }
}

__global__ void bandsplit_naive(const float* __restrict__ x,
                                const float* __restrict__ pre_w,
                                const float* __restrict__ pre_b,
                                const float* __restrict__ post_w,
                                const float* __restrict__ post_b,
                                const float* __restrict__ mel,
                                const float* __restrict__ mask,
                                const float* __restrict__ ola,
                                const int*   __restrict__ idx,
                                float* __restrict__ out,
                                int W)
{
    const int i1 = 2 * W;
    extern __shared__ float sh[];
    float* g = sh;
    float* z = sh + i1;
    const int m = blockIdx.x, k = blockIdx.y;
    const int b = m / T_LEN, t = m % T_LEN;
    const int tid = threadIdx.x;
    for (int j = tid; j < i1; j += 128) {
        int w = j >> 1, c = j & 1;
        int f = idx[k * W + w];
        g[j] = x[((b * C_INC + c) * T_LEN + t) * F_BINS + f] * mel[k * W + w] * mask[k * W + w];
    }
    __syncthreads();
    {
        int d = tid;
        float a = pre_b[k * D_OUTC + d];
        for (int i = 0; i < i1; ++i) a += g[i] * pre_w[(k * i1 + i) * D_OUTC + d];
        z[d] = a;
    }
    __syncthreads();
    for (int o = tid; o < i1; o += 128) {
        int w = o >> 1, c = o & 1;
        float mk = mask[k * W + w];
        if (mk == 0.f) continue;
        float a = post_b[k * i1 + o];
        for (int d = 0; d < D_OUTC; ++d) a += z[d] * post_w[(k * D_OUTC + d) * i1 + o];
        int f = idx[k * W + w];
        atomicAdd(&out[((b * C_INC + c) * T_LEN + t) * F_BINS + f], a * mk / ola[f]);
    }
}

extern "C" void kernel_launch(void* const* d_in, const int* in_sizes, int n_in,
                              void* d_out, int out_size, void* d_ws, size_t ws_size,
                              hipStream_t stream) {
    const float* x      = (const float*)d_in[0];
    const float* pre_w  = (const float*)d_in[1];
    const float* pre_b  = (const float*)d_in[2];
    const float* post_w = (const float*)d_in[3];
    const float* post_b = (const float*)d_in[4];
    const float* mel    = (const float*)d_in[5];
    const float* mask   = (const float*)d_in[6];
    const float* ola    = (const float*)d_in[7];
    const int*   idxp   = (const int*)d_in[8];
    float* out = (float*)d_out;

    const int W  = in_sizes[8] / N_BANDS;
    const int i1 = 2 * W;
    const int Mrows = in_sizes[0] / (C_INC * F_BINS);
    const int K1PA = 2 * ((W + 15) & ~15);

    const size_t S1 = (size_t)N_BANDS * D_OUTC * K1PA;
    const size_t wbytes   = 4 * S1;                              // 2 arrays x 2B
    const size_t pbs_off  = (wbytes + 15) & ~(size_t)15;
    const size_t inv_off  = (pbs_off + (size_t)N_BANDS * i1 * 4 + 15) & ~(size_t)15;
    const size_t len_off  = inv_off + (size_t)F_BINS * 4 * 4;
    const size_t lenp_off = len_off + N_BANDS * 4;
    const size_t offt_off = lenp_off + N_BANDS * 4;
    const size_t strt_off = offt_off + (N_BANDS + 1) * 4;
    const size_t perm_off = strt_off + N_BANDS * 4;
    const size_t y_off    = (perm_off + N_BANDS * 4 + 255) & ~(size_t)255;
    const size_t need     = y_off + (size_t)Mrows * SCAP * sizeof(__half);

    if (W <= MAX_W && (Mrows % 64) == 0 && (Mrows % T_LEN) == 0 && ws_size >= need) {
        char* ws = (char*)d_ws;
        unsigned short* wB1h = (unsigned short*)ws;
        unsigned short* wB2h = wB1h + S1;
        float* postbS = (float*)(ws + pbs_off);
        int* inv   = (int*)(ws + inv_off);
        int* lenT  = (int*)(ws + len_off);
        int* lenPT = (int*)(ws + lenp_off);
        int* offT  = (int*)(ws + offt_off);
        int* startT= (int*)(ws + strt_off);
        int* permT = (int*)(ws + perm_off);
        __half* y  = (__half*)(ws + y_off);

        k_len<<<N_BANDS, 64, 0, stream>>>(mask, idxp, W, lenT, startT);
        k_scan<<<1, N_BANDS, 0, stream>>>(lenT, lenPT, offT, permT);
        dim3 g1(K1PA / 32, N_BANDS);
        prep_w1<<<g1, 256, 0, stream>>>(pre_w, mel, mask, lenPT, wB1h, W, i1, K1PA);
        dim3 g2(K1PA / 2, N_BANDS);
        prep_w2<<<g2, 256, 0, stream>>>(post_w, post_b, mask, idxp, ola, wB2h, postbS,
                                        W, i1, K1PA);
        k_inv2<<<(F_BINS + 255) / 256, 256, 0, stream>>>(startT, lenT, offT, inv);
        const int nmt = Mrows / 64;
        bandsplit_main<<<nmt * N_BANDS, 128, 0, stream>>>(x, wB1h, wB2h,
                                                 pre_b, postbS, lenT, lenPT, offT, startT,
                                                 permT, y, i1, K1PA, nmt);
        k_merge<<<4096, 256, 0, stream>>>(y, inv, out, Mrows);
        return;
    }

    hipMemsetAsync(d_out, 0, (size_t)out_size * sizeof(float), stream);
    if (W <= MAX_W && (Mrows % MT) == 0) {
        dim3 grid(Mrows / MT, N_BANDS);
        bandsplit_fused<<<grid, TPB, 0, stream>>>(x, pre_w, pre_b, post_w, post_b,
                                                  mel, mask, ola, idxp, out, W);
    } else {
        dim3 grid(Mrows, N_BANDS);
        size_t shmem = (size_t)(2 * W + D_OUTC) * sizeof(float);
        bandsplit_naive<<<grid, 128, shmem, stream>>>(x, pre_w, pre_b, post_w, post_b,
                                                      mel, mask, ola, idxp, out, W);
    }
}

// Round 17
// 120.102 us; speedup vs baseline: 1.1007x; 1.1007x over previous
//
#include <hip/hip_runtime.h>
#include <hip/hip_fp16.h>

typedef __attribute__((ext_vector_type(8))) short short8;
typedef __attribute__((ext_vector_type(4))) float f32x4;

constexpr int D_OUTC = 128;
constexpr int T_LEN  = 512;
constexpr int C_INC  = 2;
constexpr int F_BINS = 1025;
constexpr int N_BANDS= 128;
constexpr int MAX_W  = 80;
constexpr int SCAP   = 4224;

// RNE convert f32[8] -> bf16x8
__device__ inline short8 cvt8(const float v[8]) {
  short8 h;
  #pragma unroll
  for (int j = 0; j < 8; ++j) {
    unsigned u = __float_as_uint(v[j]);
    unsigned r = u + 0x7FFFu + ((u >> 16) & 1u);
    h[j] = (short)(r >> 16);
  }
  return h;
}

// ============ meta A: per-band len/start (128 blocks x 64 lanes, PARALLEL) ============
// R14 lesson: fusing this into one single-block kernel serialized ~100us on 1 CU.
__global__ void k_len(const float* __restrict__ mask, const int* __restrict__ idx, int W,
                      int* __restrict__ lenT, int* __restrict__ startT) {
  const int k = blockIdx.x;
  const int lane = threadIdx.x;
  int cnt = 0;
  for (int w = lane; w < W; w += 64) cnt += (mask[k * W + w] != 0.f) ? 1 : 0;
  #pragma unroll
  for (int s = 32; s > 0; s >>= 1) cnt += __shfl_xor(cnt, s, 64);
  if (lane == 0) { lenT[k] = cnt; startT[k] = idx[k * W]; }
}
// ============ meta B: lenP + scan + LPT permutation (1 tiny block) ============
__global__ void k_scan(const int* __restrict__ lenT, int* __restrict__ lenPT,
                       int* __restrict__ offT, int* __restrict__ permT) {
  const int k = threadIdx.x;
  int l = lenT[k];
  lenPT[k] = (l + 15) & ~15;
  __shared__ int sh[N_BANDS];
  __shared__ int sl[N_BANDS];
  sh[k] = 2 * l;
  sl[k] = l;
  __syncthreads();
  for (int s = 1; s < N_BANDS; s <<= 1) {
    int t = (k >= s) ? sh[k - s] : 0;
    __syncthreads();
    sh[k] += t;
    __syncthreads();
  }
  offT[k] = sh[k] - 2 * l;
  if (k == N_BANDS - 1) offT[N_BANDS] = sh[k];
  // LPT rank: descending len, band index tiebreak (deterministic bijection)
  int rank = 0;
  for (int j = 0; j < N_BANDS; ++j)
    rank += (sl[j] > l) || (sl[j] == l && j < k);
  permT[rank] = k;
}
// ============ meta C: inverse map, grid over f ============
__global__ void k_inv2(const int* __restrict__ startT, const int* __restrict__ lenT,
                       const int* __restrict__ offT, int* __restrict__ inv) {
  int f = blockIdx.x * 256 + threadIdx.x;
  if (f >= F_BINS) return;
  int r0 = -1, r1 = -1, r2 = -1, r3 = -1;
  int n = 0;
  for (int k = 0; k < N_BANDS; ++k) {
    unsigned rel = (unsigned)(f - startT[k]);
    if (rel < (unsigned)lenT[k]) {
      int v = offT[k] + 2 * (int)rel;
      if (n == 0) r0 = v; else if (n == 1) r1 = v; else if (n == 2) r2 = v; else r3 = v;
      ++n;
    }
  }
  *(int4*)&inv[f * 4] = make_int4(r0, r1, r2, r3);
}

// ============ W1' prep: fold mel*mask, planar i' = w + c*lenP, bf16-hi (RNE) ============
__global__ void prep_w1(const float* __restrict__ pre_w, const float* __restrict__ mel,
                        const float* __restrict__ mask, const int* __restrict__ lenPT,
                        unsigned short* __restrict__ hh,
                        int W, int i1, int K1PA) {
  const int band = blockIdx.y;
  const int ip = blockIdx.x * 32 + (threadIdx.x & 31);
  const int lp = lenPT[band];
  const int c  = (ip >= lp) ? 1 : 0;
  const int w  = ip - (c ? lp : 0);
  const bool live = (ip < 2 * lp) && (w < W);
  float s = 0.f; int row = 0;
  if (live) { s = mel[band * W + w] * mask[band * W + w]; row = 2 * w + c; }
  for (int d = (threadIdx.x >> 5); d < D_OUTC; d += 8) {
    float v = live ? s * pre_w[((size_t)band * i1 + row) * D_OUTC + d] : 0.f;
    unsigned u = __float_as_uint(v);
    unsigned r = u + 0x7FFFu + ((u >> 16) & 1u);
    hh[((size_t)(band * D_OUTC + d)) * K1PA + ip] = (unsigned short)(r >> 16);
  }
}

// ============ W2' prep: fold mask/ola, bf16-hi (RNE); also emits postbS ============
__global__ void prep_w2(const float* __restrict__ post_w, const float* __restrict__ post_b,
                        const float* __restrict__ mask,
                        const int* __restrict__ idx, const float* __restrict__ ola,
                        unsigned short* __restrict__ hh, float* __restrict__ postbS,
                        int W, int i1, int K1PA) {
  const int band = blockIdx.y;
  const int o  = blockIdx.x * 2 + (threadIdx.x >> 7);
  const int dd = threadIdx.x & 127;
  float s = 0.f;
  if (o < i1) {
    int w = o >> 1;
    float mk = mask[band * W + w];
    if (mk != 0.f) s = mk / ola[idx[band * W + w]];
  }
  float v = (o < i1) ? s * post_w[((size_t)band * D_OUTC + dd) * i1 + o] : 0.f;
  unsigned u = __float_as_uint(v);
  unsigned r = u + 0x7FFFu + ((u >> 16) & 1u);
  hh[((size_t)(band * K1PA + o)) * D_OUTC + dd] = (unsigned short)(r >> 16);
  if (dd == 0 && o < i1)
    postbS[band * i1 + o] = s * post_b[band * i1 + o];   // s==0 when masked
}

// ============ main: band-major+LPT, 64-row blocks (2 waves), 32-row waves ============
// Proven-best configuration (R15, 119.8us total): one-pass GEMM1 (64 acc regs,
// 4 waves/SIMD), x RNE-bf16 / W RNE-bf16 / z RNE-bf16, B-loads shared across
// two 16-row halves, GEMM2 ot-paired, y fp16 pre-scaled.
// R16 lesson: acc-splitting (two d-passes) raises occupancy but doubles the
// GEMM1 serial chain -> net loss. Do not split.
__global__ __launch_bounds__(128, 4)
void bandsplit_main(const float* __restrict__ x,
                    const unsigned short* __restrict__ wB1h,
                    const unsigned short* __restrict__ wB2h,
                    const float* __restrict__ pre_b,
                    const float* __restrict__ postbS,
                    const int* __restrict__ lenT,
                    const int* __restrict__ lenPT,
                    const int* __restrict__ offT,
                    const int* __restrict__ startT,
                    const int* __restrict__ permT,
                    __half* __restrict__ y,
                    int i1, int K1PA, int nmt)
{
  const int bid  = blockIdx.x;
  const int band = permT[bid / nmt];         // LPT: heavy bands first
  const int mt   = bid - (bid / nmt) * nmt;

  const int lenv = lenT[band];
  if (lenv == 0) return;
  const int lp   = lenPT[band];
  const int nks  = lp >> 4;
  const int i1e  = 2 * lenv;
  const int nOT  = (i1e + 15) >> 4;
  const int offk = offT[band];
  const int strt = startT[band];

  const int mbase = mt * 64;
  const int b  = mbase >> 9;                 // 64 | 512
  const int t0 = mbase & 511;
  const int tid  = threadIdx.x;
  const int lane = tid & 63;
  const int wid  = tid >> 6;                 // 0..1
  const int lr = lane & 15, lk = lane >> 4;
  const int m0 = wid * 32;

  __shared__ float zAll[2][16 * 132];
  float* zw = zAll[wid];

  const float* xr0A = x + ((size_t)(b * C_INC) * T_LEN + (t0 + m0 + lr)) * F_BINS + strt;
  const float* xr0B = xr0A + (size_t)16 * F_BINS;
  const size_t xcs = (size_t)T_LEN * F_BINS;

  // ---- GEMM1: two 16-row halves share every B-load ----
  f32x4 a1A[8] = {}, a1B[8] = {};
  const unsigned short* b1h = wB1h + ((size_t)(band * D_OUTC) + lr) * K1PA;

  for (int ks = 0; ks < nks; ++ks) {
    const int i0 = ks * 32 + lk * 8;
    const int cs = (i0 >= lp) ? 1 : 0;
    const int w0 = i0 - (cs ? lp : 0);
    const float* xrA = xr0A + (cs ? xcs : 0) + w0;
    const float* xrB = xr0B + (cs ? xcs : 0) + w0;
    float xvA[8], xvB[8];
    if (w0 + 8 <= lenv) {
      float4 q0, q1, q2, q3;
      __builtin_memcpy(&q0, xrA,     16);
      __builtin_memcpy(&q1, xrA + 4, 16);
      __builtin_memcpy(&q2, xrB,     16);
      __builtin_memcpy(&q3, xrB + 4, 16);
      xvA[0]=q0.x; xvA[1]=q0.y; xvA[2]=q0.z; xvA[3]=q0.w;
      xvA[4]=q1.x; xvA[5]=q1.y; xvA[6]=q1.z; xvA[7]=q1.w;
      xvB[0]=q2.x; xvB[1]=q2.y; xvB[2]=q2.z; xvB[3]=q2.w;
      xvB[4]=q3.x; xvB[5]=q3.y; xvB[6]=q3.z; xvB[7]=q3.w;
    } else {
      #pragma unroll
      for (int j = 0; j < 8; ++j) {
        bool ok = (w0 + j < lenv);
        xvA[j] = ok ? xrA[j] : 0.f;
        xvB[j] = ok ? xrB[j] : 0.f;
      }
    }
    const short8 ahA = cvt8(xvA);
    const short8 ahB = cvt8(xvB);

    #pragma unroll
    for (int half = 0; half < 2; ++half) {
      short8 BH[4];
      #pragma unroll
      for (int t = 0; t < 4; ++t) {
        const int dt = half * 4 + t;
        BH[t] = *(const short8*)&b1h[(size_t)dt * 16 * K1PA + i0];
      }
      #pragma unroll
      for (int t = 0; t < 4; ++t) {
        const int dt = half * 4 + t;
        a1A[dt] = __builtin_amdgcn_mfma_f32_16x16x32_bf16(ahA, BH[t], a1A[dt], 0, 0, 0);
        a1B[dt] = __builtin_amdgcn_mfma_f32_16x16x32_bf16(ahB, BH[t], a1B[dt], 0, 0, 0);
      }
    }
  }

  float pbv[8];
  #pragma unroll
  for (int dt = 0; dt < 8; ++dt) pbv[dt] = pre_b[band * D_OUTC + dt * 16 + lr];

  // ---- z transpose through per-wave LDS, half A then half B.
  // Cross-lane LDS write->read: barriers are mandatory (R4 race lesson).
  short8 zhA[4], zhB[4];
  #pragma unroll
  for (int dt = 0; dt < 8; ++dt)
    #pragma unroll
    for (int r = 0; r < 4; ++r)
      zw[(lk * 4 + r) * 132 + dt * 16 + lr] = a1A[dt][r] + pbv[dt];
  __syncthreads();
  #pragma unroll
  for (int ks = 0; ks < 4; ++ks) {
    float zv[8];
    *(float4*)&zv[0] = *(const float4*)&zw[lr * 132 + ks * 32 + lk * 8];
    *(float4*)&zv[4] = *(const float4*)&zw[lr * 132 + ks * 32 + lk * 8 + 4];
    zhA[ks] = cvt8(zv);
  }
  __syncthreads();
  #pragma unroll
  for (int dt = 0; dt < 8; ++dt)
    #pragma unroll
    for (int r = 0; r < 4; ++r)
      zw[(lk * 4 + r) * 132 + dt * 16 + lr] = a1B[dt][r] + pbv[dt];
  __syncthreads();
  #pragma unroll
  for (int ks = 0; ks < 4; ++ks) {
    float zv[8];
    *(float4*)&zv[0] = *(const float4*)&zw[lr * 132 + ks * 32 + lk * 8];
    *(float4*)&zv[4] = *(const float4*)&zw[lr * 132 + ks * 32 + lk * 8 + 4];
    zhB[ks] = cvt8(zv);
  }

  // ---- GEMM2: 2 o-tiles per iteration; store y (fp16, pre-scaled) ----
  const unsigned short* b2h = wB2h + ((size_t)(band * K1PA) + lr) * D_OUTC;
  for (int ot = 0; ot < nOT; ot += 2) {
    const bool has2 = (ot + 1 < nOT);
    short8 B0[4], B1[4];
    #pragma unroll
    for (int ks = 0; ks < 4; ++ks)
      B0[ks] = *(const short8*)&b2h[(size_t)ot * 16 * D_OUTC + ks * 32 + lk * 8];
    if (has2) {
      #pragma unroll
      for (int ks = 0; ks < 4; ++ks)
        B1[ks] = *(const short8*)&b2h[(size_t)(ot + 1) * 16 * D_OUTC + ks * 32 + lk * 8];
    }
    f32x4 aA0 = {}, aB0 = {}, aA1 = {}, aB1 = {};
    #pragma unroll
    for (int ks = 0; ks < 4; ++ks) {
      aA0 = __builtin_amdgcn_mfma_f32_16x16x32_bf16(zhA[ks], B0[ks], aA0, 0, 0, 0);
      aB0 = __builtin_amdgcn_mfma_f32_16x16x32_bf16(zhB[ks], B0[ks], aB0, 0, 0, 0);
    }
    if (has2) {
      #pragma unroll
      for (int ks = 0; ks < 4; ++ks) {
        aA1 = __builtin_amdgcn_mfma_f32_16x16x32_bf16(zhA[ks], B1[ks], aA1, 0, 0, 0);
        aB1 = __builtin_amdgcn_mfma_f32_16x16x32_bf16(zhB[ks], B1[ks], aB1, 0, 0, 0);
      }
    }
    {
      const int o = ot * 16 + lr;
      if (o < i1e) {
        const float pb = postbS[band * i1 + o];
        const size_t ybA = ((size_t)(b * T_LEN + t0 + m0 + lk * 4)) * SCAP + offk + o;
        const size_t ybB = ybA + (size_t)16 * SCAP;
        #pragma unroll
        for (int r = 0; r < 4; ++r) {
          y[ybA + (size_t)r * SCAP] = __float2half_rn(aA0[r] + pb);
          y[ybB + (size_t)r * SCAP] = __float2half_rn(aB0[r] + pb);
        }
      }
    }
    if (has2) {
      const int o = (ot + 1) * 16 + lr;
      if (o < i1e) {
        const float pb = postbS[band * i1 + o];
        const size_t ybA = ((size_t)(b * T_LEN + t0 + m0 + lk * 4)) * SCAP + offk + o;
        const size_t ybB = ybA + (size_t)16 * SCAP;
        #pragma unroll
        for (int r = 0; r < 4; ++r) {
          y[ybA + (size_t)r * SCAP] = __float2half_rn(aA1[r] + pb);
          y[ybB + (size_t)r * SCAP] = __float2half_rn(aB1[r] + pb);
        }
      }
    }
  }
}

// ============ merge: half2 loads cover both channels; two coalesced row stores ============
__global__ __launch_bounds__(256, 8)
void k_merge(const __half* __restrict__ y, const int* __restrict__ inv,
             float* __restrict__ out, int nbt) {
  const size_t crow = (size_t)T_LEN * F_BINS;   // c-stride in out
  for (int row = blockIdx.x; row < nbt; row += gridDim.x) {   // row = b*T + t
    const int t = row & 511;
    const int b = row >> 9;
    const size_t ybase = (size_t)row * SCAP;
    float* o0 = out + ((size_t)(b * C_INC) * T_LEN + t) * F_BINS;  // c=0 row
    float* o1 = o0 + crow;                                          // c=1 row
    for (int f = threadIdx.x; f < F_BINS; f += 256) {
      const int4 iv = *reinterpret_cast<const int4*>(&inv[f * 4]);
      float s0 = 0.f, s1 = 0.f;
      if (iv.x >= 0) {
        const __half2 h = *reinterpret_cast<const __half2*>(&y[ybase + iv.x]);
        s0 += __half2float(h.x); s1 += __half2float(h.y);
      }
      if (iv.y >= 0) {
        const __half2 h = *reinterpret_cast<const __half2*>(&y[ybase + iv.y]);
        s0 += __half2float(h.x); s1 += __half2float(h.y);
      }
      if (iv.z >= 0) {
        const __half2 h = *reinterpret_cast<const __half2*>(&y[ybase + iv.z]);
        s0 += __half2float(h.x); s1 += __half2float(h.y);
      }
      if (iv.w >= 0) {
        const __half2 h = *reinterpret_cast<const __half2*>(&y[ybase + iv.w]);
        s0 += __half2float(h.x); s1 += __half2float(h.y);
      }
      o0[f] = s0;
      o1[f] = s1;
    }
  }
}

// ================= fallback: fp32 fused (atomics) + naive =================
#define TPB 256
constexpr int MT     = 32;
constexpr int MAX_I1 = 2 * MAX_W;
constexpr int MAX_I1P= (MAX_I1 + 31) & ~31;
constexpr int GSTR   = 36;

__global__ __launch_bounds__(TPB, 2)
void bandsplit_fused(const float* __restrict__ x,
                     const float* __restrict__ pre_w,
                     const float* __restrict__ pre_b,
                     const float* __restrict__ post_w,
                     const float* __restrict__ post_b,
                     const float* __restrict__ mel,
                     const float* __restrict__ mask,
                     const float* __restrict__ ola,
                     const int*   __restrict__ idx,
                     float* __restrict__ out,
                     int W)
{
    const int i1  = 2 * W;
    const int I1P = (i1 + 31) & ~31;
    const int k     = blockIdx.y;
    const int mbase = blockIdx.x * MT;
    const int b     = mbase / T_LEN;
    const int t0    = mbase % T_LEN;
    const int tid = threadIdx.x;
    const int td  = tid & 31;
    const int tm  = tid >> 5;

    __shared__ float gT[MAX_I1P * GSTR];
    __shared__ float zT[D_OUTC * GSTR];
    __shared__ float wS[32 * D_OUTC];
    __shared__ float s_preb[D_OUTC];
    __shared__ float s_postb[MAX_I1];
    __shared__ float s_melmask[MAX_W];
    __shared__ float s_mask[MAX_W];
    __shared__ float s_iola[MAX_W];
    __shared__ int   s_idx[MAX_W];

    for (int j = tid; j < W; j += TPB) {
        int   f  = idx[k * W + j];
        float mv = mel[k * W + j];
        float mk = mask[k * W + j];
        s_idx[j]     = f;
        s_melmask[j] = mv * mk;
        s_mask[j]    = mk;
        s_iola[j]    = 1.0f / ola[f];
    }
    for (int j = tid; j < D_OUTC; j += TPB) s_preb[j]  = pre_b[k * D_OUTC + j];
    for (int j = tid; j < i1;     j += TPB) s_postb[j] = post_b[k * i1 + j];
    for (int j = tid; j < I1P * GSTR; j += TPB) gT[j] = 0.f;
    __syncthreads();

    for (int j = tid; j < MT * i1; j += TPB) {
        int w  = j % W;
        int cm = j / W;
        int c  = cm & 1;
        int ml = cm >> 1;
        int f  = s_idx[w];
        float v = x[((b * C_INC + c) * T_LEN + (t0 + ml)) * F_BINS + f] * s_melmask[w];
        gT[(2 * w + c) * GSTR + ml] = v;
    }
    __syncthreads();

    float az[4][4] = {};
    for (int i0 = 0; i0 < I1P; i0 += 32) {
        for (int j = tid; j < 32 * D_OUTC; j += TPB) {
            int ii = j >> 7, d = j & 127;
            int i  = i0 + ii;
            wS[j] = (i < i1) ? pre_w[(k * i1 + i) * D_OUTC + d] : 0.f;
        }
        __syncthreads();
        #pragma unroll 8
        for (int ii = 0; ii < 32; ++ii) {
            const float4 wv = *reinterpret_cast<const float4*>(&wS[ii * D_OUTC + td * 4]);
            const float4 gv = *reinterpret_cast<const float4*>(&gT[(i0 + ii) * GSTR + tm * 4]);
            az[0][0] += gv.x * wv.x; az[0][1] += gv.x * wv.y; az[0][2] += gv.x * wv.z; az[0][3] += gv.x * wv.w;
            az[1][0] += gv.y * wv.x; az[1][1] += gv.y * wv.y; az[1][2] += gv.y * wv.z; az[1][3] += gv.y * wv.w;
            az[2][0] += gv.z * wv.x; az[2][1] += gv.z * wv.y; az[2][2] += gv.z * wv.z; az[2][3] += gv.z * wv.w;
            az[3][0] += gv.w * wv.x; az[3][1] += gv.w * wv.y; az[3][2] += gv.w * wv.z; az[3][3] += gv.w * wv.w;
        }
        __syncthreads();
    }
    #pragma unroll
    for (int jj = 0; jj < 4; ++jj) {
        int d = td * 4 + jj;
        float bb = s_preb[d];
        #pragma unroll
        for (int r = 0; r < 4; ++r)
            zT[d * GSTR + tm * 4 + r] = az[r][jj] + bb;
    }
    __syncthreads();

    const int NOG = (i1 + 127) >> 7;
    for (int og = 0; og < NOG; ++og) {
        float ay[4][4] = {};
        for (int d0 = 0; d0 < D_OUTC; d0 += 32) {
            for (int j = tid; j < 32 * D_OUTC; j += TPB) {
                int dd = j >> 7, oo = j & 127;
                int o  = og * 128 + oo;
                wS[j] = (o < i1) ? post_w[(k * D_OUTC + d0 + dd) * i1 + o] : 0.f;
            }
            __syncthreads();
            #pragma unroll 8
            for (int dd = 0; dd < 32; ++dd) {
                const float4 wv = *reinterpret_cast<const float4*>(&wS[dd * D_OUTC + td * 4]);
                const float4 zv = *reinterpret_cast<const float4*>(&zT[(d0 + dd) * GSTR + tm * 4]);
                ay[0][0] += zv.x * wv.x; ay[0][1] += zv.x * wv.y; ay[0][2] += zv.x * wv.z; ay[0][3] += zv.x * wv.w;
                ay[1][0] += zv.y * wv.x; ay[1][1] += zv.y * wv.y; ay[1][2] += zv.y * wv.z; ay[1][3] += zv.y * wv.w;
                ay[2][0] += zv.z * wv.x; ay[2][1] += zv.z * wv.y; ay[2][2] += zv.z * wv.z; ay[2][3] += zv.z * wv.w;
                ay[3][0] += zv.w * wv.x; ay[3][1] += zv.w * wv.y; ay[3][2] += zv.w * wv.z; ay[3][3] += zv.w * wv.w;
            }
            __syncthreads();
        }
        #pragma unroll
        for (int jj = 0; jj < 4; ++jj) {
            int o = og * 128 + td * 4 + jj;
            if (o < i1) {
                int w = o >> 1, c = o & 1;
                float mk = s_mask[w];
                if (mk != 0.f) {
                    int f = s_idx[w];
                    float scale = mk * s_iola[w];
                    float bb = s_postb[o];
                    #pragma unroll
                    for (int r = 0; r < 4; ++r) {
                        int ml = tm * 4 + r;
                        float val = (ay[r][jj] + bb) * scale;
                        atomicAdd(&out[((b * C_INC + c) * T_LEN + (t0 + ml)) * F_BINS + f], val);
                    }
                }
            }
        }
    }
}

__global__ void bandsplit_naive(const float* __restrict__ x,
                                const float* __restrict__ pre_w,
                                const float* __restrict__ pre_b,
                                const float* __restrict__ post_w,
                                const float* __restrict__ post_b,
                                const float* __restrict__ mel,
                                const float* __restrict__ mask,
                                const float* __restrict__ ola,
                                const int*   __restrict__ idx,
                                float* __restrict__ out,
                                int W)
{
    const int i1 = 2 * W;
    extern __shared__ float sh[];
    float* g = sh;
    float* z = sh + i1;
    const int m = blockIdx.x, k = blockIdx.y;
    const int b = m / T_LEN, t = m % T_LEN;
    const int tid = threadIdx.x;
    for (int j = tid; j < i1; j += 128) {
        int w = j >> 1, c = j & 1;
        int f = idx[k * W + w];
        g[j] = x[((b * C_INC + c) * T_LEN + t) * F_BINS + f] * mel[k * W + w] * mask[k * W + w];
    }
    __syncthreads();
    {
        int d = tid;
        float a = pre_b[k * D_OUTC + d];
        for (int i = 0; i < i1; ++i) a += g[i] * pre_w[(k * i1 + i) * D_OUTC + d];
        z[d] = a;
    }
    __syncthreads();
    for (int o = tid; o < i1; o += 128) {
        int w = o >> 1, c = o & 1;
        float mk = mask[k * W + w];
        if (mk == 0.f) continue;
        float a = post_b[k * i1 + o];
        for (int d = 0; d < D_OUTC; ++d) a += z[d] * post_w[(k * D_OUTC + d) * i1 + o];
        int f = idx[k * W + w];
        atomicAdd(&out[((b * C_INC + c) * T_LEN + t) * F_BINS + f], a * mk / ola[f]);
    }
}

extern "C" void kernel_launch(void* const* d_in, const int* in_sizes, int n_in,
                              void* d_out, int out_size, void* d_ws, size_t ws_size,
                              hipStream_t stream) {
    const float* x      = (const float*)d_in[0];
    const float* pre_w  = (const float*)d_in[1];
    const float* pre_b  = (const float*)d_in[2];
    const float* post_w = (const float*)d_in[3];
    const float* post_b = (const float*)d_in[4];
    const float* mel    = (const float*)d_in[5];
    const float* mask   = (const float*)d_in[6];
    const float* ola    = (const float*)d_in[7];
    const int*   idxp   = (const int*)d_in[8];
    float* out = (float*)d_out;

    const int W  = in_sizes[8] / N_BANDS;
    const int i1 = 2 * W;
    const int Mrows = in_sizes[0] / (C_INC * F_BINS);
    const int K1PA = 2 * ((W + 15) & ~15);

    const size_t S1 = (size_t)N_BANDS * D_OUTC * K1PA;
    const size_t wbytes   = 4 * S1;                              // 2 arrays x 2B
    const size_t pbs_off  = (wbytes + 15) & ~(size_t)15;
    const size_t inv_off  = (pbs_off + (size_t)N_BANDS * i1 * 4 + 15) & ~(size_t)15;
    const size_t len_off  = inv_off + (size_t)F_BINS * 4 * 4;
    const size_t lenp_off = len_off + N_BANDS * 4;
    const size_t offt_off = lenp_off + N_BANDS * 4;
    const size_t strt_off = offt_off + (N_BANDS + 1) * 4;
    const size_t perm_off = strt_off + N_BANDS * 4;
    const size_t y_off    = (perm_off + N_BANDS * 4 + 255) & ~(size_t)255;
    const size_t need     = y_off + (size_t)Mrows * SCAP * sizeof(__half);

    if (W <= MAX_W && (Mrows % 64) == 0 && (Mrows % T_LEN) == 0 && ws_size >= need) {
        char* ws = (char*)d_ws;
        unsigned short* wB1h = (unsigned short*)ws;
        unsigned short* wB2h = wB1h + S1;
        float* postbS = (float*)(ws + pbs_off);
        int* inv   = (int*)(ws + inv_off);
        int* lenT  = (int*)(ws + len_off);
        int* lenPT = (int*)(ws + lenp_off);
        int* offT  = (int*)(ws + offt_off);
        int* startT= (int*)(ws + strt_off);
        int* permT = (int*)(ws + perm_off);
        __half* y  = (__half*)(ws + y_off);

        k_len<<<N_BANDS, 64, 0, stream>>>(mask, idxp, W, lenT, startT);
        k_scan<<<1, N_BANDS, 0, stream>>>(lenT, lenPT, offT, permT);
        dim3 g1(K1PA / 32, N_BANDS);
        prep_w1<<<g1, 256, 0, stream>>>(pre_w, mel, mask, lenPT, wB1h, W, i1, K1PA);
        dim3 g2(K1PA / 2, N_BANDS);
        prep_w2<<<g2, 256, 0, stream>>>(post_w, post_b, mask, idxp, ola, wB2h, postbS,
                                        W, i1, K1PA);
        k_inv2<<<(F_BINS + 255) / 256, 256, 0, stream>>>(startT, lenT, offT, inv);
        const int nmt = Mrows / 64;
        bandsplit_main<<<nmt * N_BANDS, 128, 0, stream>>>(x, wB1h, wB2h,
                                                 pre_b, postbS, lenT, lenPT, offT, startT,
                                                 permT, y, i1, K1PA, nmt);
        k_merge<<<4096, 256, 0, stream>>>(y, inv, out, Mrows);
        return;
    }

    hipMemsetAsync(d_out, 0, (size_t)out_size * sizeof(float), stream);
    if (W <= MAX_W && (Mrows % MT) == 0) {
        dim3 grid(Mrows / MT, N_BANDS);
        bandsplit_fused<<<grid, TPB, 0, stream>>>(x, pre_w, pre_b, post_w, post_b,
                                                  mel, mask, ola, idxp, out, W);
    } else {
        dim3 grid(Mrows, N_BANDS);
        size_t shmem = (size_t)(2 * W + D_OUTC) * sizeof(float);
        bandsplit_naive<<<grid, 128, shmem, stream>>>(x, pre_w, pre_b, post_w, post_b,
                                                      mel, mask, ola, idxp, out, W);
    }
}

// Round 18
// 118.474 us; speedup vs baseline: 1.1159x; 1.0137x over previous
//
#include <hip/hip_runtime.h>
#include <hip/hip_fp16.h>

typedef __attribute__((ext_vector_type(8))) short short8;
typedef __attribute__((ext_vector_type(4))) float f32x4;

constexpr int D_OUTC = 128;
constexpr int T_LEN  = 512;
constexpr int C_INC  = 2;
constexpr int F_BINS = 1025;
constexpr int N_BANDS= 128;
constexpr int MAX_W  = 80;
constexpr int SCAP   = 4224;

__device__ inline unsigned short bf16r(float f) {
  unsigned u = __float_as_uint(f);
  unsigned r = u + 0x7FFFu + ((u >> 16) & 1u);
  return (unsigned short)(r >> 16);
}
// RNE convert f32[8] -> bf16x8
__device__ inline short8 cvt8(const float v[8]) {
  short8 h;
  #pragma unroll
  for (int j = 0; j < 8; ++j) h[j] = (short)bf16r(v[j]);
  return h;
}

// ============ meta A: per-band len/start (parallel; R14 lesson: never single-block) ============
__global__ void k_len(const float* __restrict__ mask, const int* __restrict__ idx, int W,
                      int* __restrict__ lenT, int* __restrict__ startT) {
  const int k = blockIdx.x;
  const int lane = threadIdx.x;
  int cnt = 0;
  for (int w = lane; w < W; w += 64) cnt += (mask[k * W + w] != 0.f) ? 1 : 0;
  #pragma unroll
  for (int s = 32; s > 0; s >>= 1) cnt += __shfl_xor(cnt, s, 64);
  if (lane == 0) { lenT[k] = cnt; startT[k] = idx[k * W]; }
}
// ============ meta B: lenP + scan + LPT permutation (1 tiny block) ============
__global__ void k_scan(const int* __restrict__ lenT, int* __restrict__ lenPT,
                       int* __restrict__ offT, int* __restrict__ permT) {
  const int k = threadIdx.x;
  int l = lenT[k];
  lenPT[k] = (l + 15) & ~15;
  __shared__ int sh[N_BANDS];
  __shared__ int sl[N_BANDS];
  sh[k] = 2 * l;
  sl[k] = l;
  __syncthreads();
  for (int s = 1; s < N_BANDS; s <<= 1) {
    int t = (k >= s) ? sh[k - s] : 0;
    __syncthreads();
    sh[k] += t;
    __syncthreads();
  }
  offT[k] = sh[k] - 2 * l;
  if (k == N_BANDS - 1) offT[N_BANDS] = sh[k];
  int rank = 0;
  for (int j = 0; j < N_BANDS; ++j)
    rank += (sl[j] > l) || (sl[j] == l && j < k);
  permT[rank] = k;
}
// ============ meta C: inverse map, grid over f ============
__global__ void k_inv2(const int* __restrict__ startT, const int* __restrict__ lenT,
                       const int* __restrict__ offT, int* __restrict__ inv) {
  int f = blockIdx.x * 256 + threadIdx.x;
  if (f >= F_BINS) return;
  int r0 = -1, r1 = -1, r2 = -1, r3 = -1;
  int n = 0;
  for (int k = 0; k < N_BANDS; ++k) {
    unsigned rel = (unsigned)(f - startT[k]);
    if (rel < (unsigned)lenT[k]) {
      int v = offT[k] + 2 * (int)rel;
      if (n == 0) r0 = v; else if (n == 1) r1 = v; else if (n == 2) r2 = v; else r3 = v;
      ++n;
    }
  }
  *(int4*)&inv[f * 4] = make_int4(r0, r1, r2, r3);
}

// ============ W1' prep (COALESCED, LDS tile transpose) ============
// read: consecutive threads -> consecutive d of pre_w (512B runs);
// write: consecutive threads -> consecutive ip of hh. Numerics identical.
__global__ __launch_bounds__(256)
void prep_w1(const float* __restrict__ pre_w, const float* __restrict__ mel,
             const float* __restrict__ mask, const int* __restrict__ lenPT,
             unsigned short* __restrict__ hh,
             int W, int i1, int K1PA) {
  const int band = blockIdx.y;
  const int ip0  = blockIdx.x * 32;
  const int lp   = lenPT[band];
  __shared__ unsigned short tile[32][136];   // [ip][d], +8 pad
  const int d = threadIdx.x & 127;
  for (int r = threadIdx.x >> 7; r < 32; r += 2) {
    const int ip = ip0 + r;
    const int c  = (ip >= lp) ? 1 : 0;
    const int w  = ip - (c ? lp : 0);
    float v = 0.f;
    if ((ip < 2 * lp) && (w < W)) {
      const float s = mel[band * W + w] * mask[band * W + w];
      v = s * pre_w[((size_t)band * i1 + 2 * w + c) * D_OUTC + d];
    }
    tile[r][d] = bf16r(v);
  }
  __syncthreads();
  const int ipl = threadIdx.x & 31;
  for (int dd = threadIdx.x >> 5; dd < D_OUTC; dd += 8)
    hh[((size_t)(band * D_OUTC + dd)) * K1PA + ip0 + ipl] = tile[ipl][dd];
}

// ============ W2' prep (COALESCED, LDS tile transpose); also emits postbS ============
// read: consecutive threads -> consecutive o of post_w (128B runs);
// write: consecutive threads -> consecutive dd of hh (256B runs).
__global__ __launch_bounds__(256)
void prep_w2(const float* __restrict__ post_w, const float* __restrict__ post_b,
             const float* __restrict__ mask,
             const int* __restrict__ idx, const float* __restrict__ ola,
             unsigned short* __restrict__ hh, float* __restrict__ postbS,
             int W, int i1, int K1PA) {
  const int band = blockIdx.y;
  const int o0   = blockIdx.x * 32;
  __shared__ unsigned short tile[32][136];   // [o][dd], +8 pad
  const int ol = threadIdx.x & 31;
  const int o  = o0 + ol;
  float s = 0.f;
  if (o < i1) {
    int w = o >> 1;
    float mk = mask[band * W + w];
    if (mk != 0.f) s = mk / ola[idx[band * W + w]];
  }
  for (int dd = threadIdx.x >> 5; dd < D_OUTC; dd += 8) {
    float v = (o < i1) ? s * post_w[((size_t)band * D_OUTC + dd) * i1 + o] : 0.f;
    tile[ol][dd] = bf16r(v);
  }
  if ((threadIdx.x >> 5) == 0 && o < i1)
    postbS[band * i1 + o] = s * post_b[band * i1 + o];   // s==0 when masked
  __syncthreads();
  const int d2 = threadIdx.x & 127;
  for (int r = threadIdx.x >> 7; r < 32; r += 2)
    hh[((size_t)(band * K1PA + o0 + r)) * D_OUTC + d2] = tile[r][d2];
}

// ============ main: band-major+LPT, 64-row blocks (2 waves), 32-row waves ============
// Proven-best configuration (R15/R17, ~120us total): one-pass GEMM1 (64 acc regs,
// 4 waves/SIMD), x/W/z all RNE-bf16, B-loads shared across two 16-row halves,
// GEMM2 ot-paired, y fp16 pre-scaled.
// R16 lesson: acc-splitting raises occupancy but doubles the GEMM1 serial chain.
__global__ __launch_bounds__(128, 4)
void bandsplit_main(const float* __restrict__ x,
                    const unsigned short* __restrict__ wB1h,
                    const unsigned short* __restrict__ wB2h,
                    const float* __restrict__ pre_b,
                    const float* __restrict__ postbS,
                    const int* __restrict__ lenT,
                    const int* __restrict__ lenPT,
                    const int* __restrict__ offT,
                    const int* __restrict__ startT,
                    const int* __restrict__ permT,
                    __half* __restrict__ y,
                    int i1, int K1PA, int nmt)
{
  const int bid  = blockIdx.x;
  const int band = permT[bid / nmt];         // LPT: heavy bands first
  const int mt   = bid - (bid / nmt) * nmt;

  const int lenv = lenT[band];
  if (lenv == 0) return;
  const int lp   = lenPT[band];
  const int nks  = lp >> 4;
  const int i1e  = 2 * lenv;
  const int nOT  = (i1e + 15) >> 4;
  const int offk = offT[band];
  const int strt = startT[band];

  const int mbase = mt * 64;
  const int b  = mbase >> 9;                 // 64 | 512
  const int t0 = mbase & 511;
  const int tid  = threadIdx.x;
  const int lane = tid & 63;
  const int wid  = tid >> 6;                 // 0..1
  const int lr = lane & 15, lk = lane >> 4;
  const int m0 = wid * 32;

  __shared__ float zAll[2][16 * 132];
  float* zw = zAll[wid];

  const float* xr0A = x + ((size_t)(b * C_INC) * T_LEN + (t0 + m0 + lr)) * F_BINS + strt;
  const float* xr0B = xr0A + (size_t)16 * F_BINS;
  const size_t xcs = (size_t)T_LEN * F_BINS;

  // ---- GEMM1: two 16-row halves share every B-load ----
  f32x4 a1A[8] = {}, a1B[8] = {};
  const unsigned short* b1h = wB1h + ((size_t)(band * D_OUTC) + lr) * K1PA;

  for (int ks = 0; ks < nks; ++ks) {
    const int i0 = ks * 32 + lk * 8;
    const int cs = (i0 >= lp) ? 1 : 0;
    const int w0 = i0 - (cs ? lp : 0);
    const float* xrA = xr0A + (cs ? xcs : 0) + w0;
    const float* xrB = xr0B + (cs ? xcs : 0) + w0;
    float xvA[8], xvB[8];
    if (w0 + 8 <= lenv) {
      float4 q0, q1, q2, q3;
      __builtin_memcpy(&q0, xrA,     16);
      __builtin_memcpy(&q1, xrA + 4, 16);
      __builtin_memcpy(&q2, xrB,     16);
      __builtin_memcpy(&q3, xrB + 4, 16);
      xvA[0]=q0.x; xvA[1]=q0.y; xvA[2]=q0.z; xvA[3]=q0.w;
      xvA[4]=q1.x; xvA[5]=q1.y; xvA[6]=q1.z; xvA[7]=q1.w;
      xvB[0]=q2.x; xvB[1]=q2.y; xvB[2]=q2.z; xvB[3]=q2.w;
      xvB[4]=q3.x; xvB[5]=q3.y; xvB[6]=q3.z; xvB[7]=q3.w;
    } else {
      #pragma unroll
      for (int j = 0; j < 8; ++j) {
        bool ok = (w0 + j < lenv);
        xvA[j] = ok ? xrA[j] : 0.f;
        xvB[j] = ok ? xrB[j] : 0.f;
      }
    }
    const short8 ahA = cvt8(xvA);
    const short8 ahB = cvt8(xvB);

    #pragma unroll
    for (int half = 0; half < 2; ++half) {
      short8 BH[4];
      #pragma unroll
      for (int t = 0; t < 4; ++t) {
        const int dt = half * 4 + t;
        BH[t] = *(const short8*)&b1h[(size_t)dt * 16 * K1PA + i0];
      }
      #pragma unroll
      for (int t = 0; t < 4; ++t) {
        const int dt = half * 4 + t;
        a1A[dt] = __builtin_amdgcn_mfma_f32_16x16x32_bf16(ahA, BH[t], a1A[dt], 0, 0, 0);
        a1B[dt] = __builtin_amdgcn_mfma_f32_16x16x32_bf16(ahB, BH[t], a1B[dt], 0, 0, 0);
      }
    }
  }

  float pbv[8];
  #pragma unroll
  for (int dt = 0; dt < 8; ++dt) pbv[dt] = pre_b[band * D_OUTC + dt * 16 + lr];

  // ---- z transpose through per-wave LDS, half A then half B.
  // Cross-lane LDS write->read: barriers are mandatory (R4 race lesson).
  short8 zhA[4], zhB[4];
  #pragma unroll
  for (int dt = 0; dt < 8; ++dt)
    #pragma unroll
    for (int r = 0; r < 4; ++r)
      zw[(lk * 4 + r) * 132 + dt * 16 + lr] = a1A[dt][r] + pbv[dt];
  __syncthreads();
  #pragma unroll
  for (int ks = 0; ks < 4; ++ks) {
    float zv[8];
    *(float4*)&zv[0] = *(const float4*)&zw[lr * 132 + ks * 32 + lk * 8];
    *(float4*)&zv[4] = *(const float4*)&zw[lr * 132 + ks * 32 + lk * 8 + 4];
    zhA[ks] = cvt8(zv);
  }
  __syncthreads();
  #pragma unroll
  for (int dt = 0; dt < 8; ++dt)
    #pragma unroll
    for (int r = 0; r < 4; ++r)
      zw[(lk * 4 + r) * 132 + dt * 16 + lr] = a1B[dt][r] + pbv[dt];
  __syncthreads();
  #pragma unroll
  for (int ks = 0; ks < 4; ++ks) {
    float zv[8];
    *(float4*)&zv[0] = *(const float4*)&zw[lr * 132 + ks * 32 + lk * 8];
    *(float4*)&zv[4] = *(const float4*)&zw[lr * 132 + ks * 32 + lk * 8 + 4];
    zhB[ks] = cvt8(zv);
  }

  // ---- GEMM2: 2 o-tiles per iteration; store y (fp16, pre-scaled) ----
  const unsigned short* b2h = wB2h + ((size_t)(band * K1PA) + lr) * D_OUTC;
  for (int ot = 0; ot < nOT; ot += 2) {
    const bool has2 = (ot + 1 < nOT);
    short8 B0[4], B1[4];
    #pragma unroll
    for (int ks = 0; ks < 4; ++ks)
      B0[ks] = *(const short8*)&b2h[(size_t)ot * 16 * D_OUTC + ks * 32 + lk * 8];
    if (has2) {
      #pragma unroll
      for (int ks = 0; ks < 4; ++ks)
        B1[ks] = *(const short8*)&b2h[(size_t)(ot + 1) * 16 * D_OUTC + ks * 32 + lk * 8];
    }
    f32x4 aA0 = {}, aB0 = {}, aA1 = {}, aB1 = {};
    #pragma unroll
    for (int ks = 0; ks < 4; ++ks) {
      aA0 = __builtin_amdgcn_mfma_f32_16x16x32_bf16(zhA[ks], B0[ks], aA0, 0, 0, 0);
      aB0 = __builtin_amdgcn_mfma_f32_16x16x32_bf16(zhB[ks], B0[ks], aB0, 0, 0, 0);
    }
    if (has2) {
      #pragma unroll
      for (int ks = 0; ks < 4; ++ks) {
        aA1 = __builtin_amdgcn_mfma_f32_16x16x32_bf16(zhA[ks], B1[ks], aA1, 0, 0, 0);
        aB1 = __builtin_amdgcn_mfma_f32_16x16x32_bf16(zhB[ks], B1[ks], aB1, 0, 0, 0);
      }
    }
    {
      const int o = ot * 16 + lr;
      if (o < i1e) {
        const float pb = postbS[band * i1 + o];
        const size_t ybA = ((size_t)(b * T_LEN + t0 + m0 + lk * 4)) * SCAP + offk + o;
        const size_t ybB = ybA + (size_t)16 * SCAP;
        #pragma unroll
        for (int r = 0; r < 4; ++r) {
          y[ybA + (size_t)r * SCAP] = __float2half_rn(aA0[r] + pb);
          y[ybB + (size_t)r * SCAP] = __float2half_rn(aB0[r] + pb);
        }
      }
    }
    if (has2) {
      const int o = (ot + 1) * 16 + lr;
      if (o < i1e) {
        const float pb = postbS[band * i1 + o];
        const size_t ybA = ((size_t)(b * T_LEN + t0 + m0 + lk * 4)) * SCAP + offk + o;
        const size_t ybB = ybA + (size_t)16 * SCAP;
        #pragma unroll
        for (int r = 0; r < 4; ++r) {
          y[ybA + (size_t)r * SCAP] = __float2half_rn(aA1[r] + pb);
          y[ybB + (size_t)r * SCAP] = __float2half_rn(aB1[r] + pb);
        }
      }
    }
  }
}

// ============ merge: half2 loads cover both channels; two coalesced row stores ============
__global__ __launch_bounds__(256, 8)
void k_merge(const __half* __restrict__ y, const int* __restrict__ inv,
             float* __restrict__ out, int nbt) {
  const size_t crow = (size_t)T_LEN * F_BINS;   // c-stride in out
  for (int row = blockIdx.x; row < nbt; row += gridDim.x) {   // row = b*T + t
    const int t = row & 511;
    const int b = row >> 9;
    const size_t ybase = (size_t)row * SCAP;
    float* o0 = out + ((size_t)(b * C_INC) * T_LEN + t) * F_BINS;  // c=0 row
    float* o1 = o0 + crow;                                          // c=1 row
    for (int f = threadIdx.x; f < F_BINS; f += 256) {
      const int4 iv = *reinterpret_cast<const int4*>(&inv[f * 4]);
      float s0 = 0.f, s1 = 0.f;
      if (iv.x >= 0) {
        const __half2 h = *reinterpret_cast<const __half2*>(&y[ybase + iv.x]);
        s0 += __half2float(h.x); s1 += __half2float(h.y);
      }
      if (iv.y >= 0) {
        const __half2 h = *reinterpret_cast<const __half2*>(&y[ybase + iv.y]);
        s0 += __half2float(h.x); s1 += __half2float(h.y);
      }
      if (iv.z >= 0) {
        const __half2 h = *reinterpret_cast<const __half2*>(&y[ybase + iv.z]);
        s0 += __half2float(h.x); s1 += __half2float(h.y);
      }
      if (iv.w >= 0) {
        const __half2 h = *reinterpret_cast<const __half2*>(&y[ybase + iv.w]);
        s0 += __half2float(h.x); s1 += __half2float(h.y);
      }
      o0[f] = s0;
      o1[f] = s1;
    }
  }
}

// ================= fallback: fp32 fused (atomics) + naive =================
#define TPB 256
constexpr int MT     = 32;
constexpr int MAX_I1 = 2 * MAX_W;
constexpr int MAX_I1P= (MAX_I1 + 31) & ~31;
constexpr int GSTR   = 36;

__global__ __launch_bounds__(TPB, 2)
void bandsplit_fused(const float* __restrict__ x,
                     const float* __restrict__ pre_w,
                     const float* __restrict__ pre_b,
                     const float* __restrict__ post_w,
                     const float* __restrict__ post_b,
                     const float* __restrict__ mel,
                     const float* __restrict__ mask,
                     const float* __restrict__ ola,
                     const int*   __restrict__ idx,
                     float* __restrict__ out,
                     int W)
{
    const int i1  = 2 * W;
    const int I1P = (i1 + 31) & ~31;
    const int k     = blockIdx.y;
    const int mbase = blockIdx.x * MT;
    const int b     = mbase / T_LEN;
    const int t0    = mbase % T_LEN;
    const int tid = threadIdx.x;
    const int td  = tid & 31;
    const int tm  = tid >> 5;

    __shared__ float gT[MAX_I1P * GSTR];
    __shared__ float zT[D_OUTC * GSTR];
    __shared__ float wS[32 * D_OUTC];
    __shared__ float s_preb[D_OUTC];
    __shared__ float s_postb[MAX_I1];
    __shared__ float s_melmask[MAX_W];
    __shared__ float s_mask[MAX_W];
    __shared__ float s_iola[MAX_W];
    __shared__ int   s_idx[MAX_W];

    for (int j = tid; j < W; j += TPB) {
        int   f  = idx[k * W + j];
        float mv = mel[k * W + j];
        float mk = mask[k * W + j];
        s_idx[j]     = f;
        s_melmask[j] = mv * mk;
        s_mask[j]    = mk;
        s_iola[j]    = 1.0f / ola[f];
    }
    for (int j = tid; j < D_OUTC; j += TPB) s_preb[j]  = pre_b[k * D_OUTC + j];
    for (int j = tid; j < i1;     j += TPB) s_postb[j] = post_b[k * i1 + j];
    for (int j = tid; j < I1P * GSTR; j += TPB) gT[j] = 0.f;
    __syncthreads();

    for (int j = tid; j < MT * i1; j += TPB) {
        int w  = j % W;
        int cm = j / W;
        int c  = cm & 1;
        int ml = cm >> 1;
        int f  = s_idx[w];
        float v = x[((b * C_INC + c) * T_LEN + (t0 + ml)) * F_BINS + f] * s_melmask[w];
        gT[(2 * w + c) * GSTR + ml] = v;
    }
    __syncthreads();

    float az[4][4] = {};
    for (int i0 = 0; i0 < I1P; i0 += 32) {
        for (int j = tid; j < 32 * D_OUTC; j += TPB) {
            int ii = j >> 7, d = j & 127;
            int i  = i0 + ii;
            wS[j] = (i < i1) ? pre_w[(k * i1 + i) * D_OUTC + d] : 0.f;
        }
        __syncthreads();
        #pragma unroll 8
        for (int ii = 0; ii < 32; ++ii) {
            const float4 wv = *reinterpret_cast<const float4*>(&wS[ii * D_OUTC + td * 4]);
            const float4 gv = *reinterpret_cast<const float4*>(&gT[(i0 + ii) * GSTR + tm * 4]);
            az[0][0] += gv.x * wv.x; az[0][1] += gv.x * wv.y; az[0][2] += gv.x * wv.z; az[0][3] += gv.x * wv.w;
            az[1][0] += gv.y * wv.x; az[1][1] += gv.y * wv.y; az[1][2] += gv.y * wv.z; az[1][3] += gv.y * wv.w;
            az[2][0] += gv.z * wv.x; az[2][1] += gv.z * wv.y; az[2][2] += gv.z * wv.z; az[2][3] += gv.z * wv.w;
            az[3][0] += gv.w * wv.x; az[3][1] += gv.w * wv.y; az[3][2] += gv.w * wv.z; az[3][3] += gv.w * wv.w;
        }
        __syncthreads();
    }
    #pragma unroll
    for (int jj = 0; jj < 4; ++jj) {
        int d = td * 4 + jj;
        float bb = s_preb[d];
        #pragma unroll
        for (int r = 0; r < 4; ++r)
            zT[d * GSTR + tm * 4 + r] = az[r][jj] + bb;
    }
    __syncthreads();

    const int NOG = (i1 + 127) >> 7;
    for (int og = 0; og < NOG; ++og) {
        float ay[4][4] = {};
        for (int d0 = 0; d0 < D_OUTC; d0 += 32) {
            for (int j = tid; j < 32 * D_OUTC; j += TPB) {
                int dd = j >> 7, oo = j & 127;
                int o  = og * 128 + oo;
                wS[j] = (o < i1) ? post_w[(k * D_OUTC + d0 + dd) * i1 + o] : 0.f;
            }
            __syncthreads();
            #pragma unroll 8
            for (int dd = 0; dd < 32; ++dd) {
                const float4 wv = *reinterpret_cast<const float4*>(&wS[dd * D_OUTC + td * 4]);
                const float4 zv = *reinterpret_cast<const float4*>(&zT[(d0 + dd) * GSTR + tm * 4]);
                ay[0][0] += zv.x * wv.x; ay[0][1] += zv.x * wv.y; ay[0][2] += zv.x * wv.z; ay[0][3] += zv.x * wv.w;
                ay[1][0] += zv.y * wv.x; ay[1][1] += zv.y * wv.y; ay[1][2] += zv.y * wv.z; ay[1][3] += zv.y * wv.w;
                ay[2][0] += zv.z * wv.x; ay[2][1] += zv.z * wv.y; ay[2][2] += zv.z * wv.z; ay[2][3] += zv.z * wv.w;
                ay[3][0] += zv.w * wv.x; ay[3][1] += zv.w * wv.y; ay[3][2] += zv.w * wv.z; ay[3][3] += zv.w * wv.w;
            }
            __syncthreads();
        }
        #pragma unroll
        for (int jj = 0; jj < 4; ++jj) {
            int o = og * 128 + td * 4 + jj;
            if (o < i1) {
                int w = o >> 1, c = o & 1;
                float mk = s_mask[w];
                if (mk != 0.f) {
                    int f = s_idx[w];
                    float scale = mk * s_iola[w];
                    float bb = s_postb[o];
                    #pragma unroll
                    for (int r = 0; r < 4; ++r) {
                        int ml = tm * 4 + r;
                        float val = (ay[r][jj] + bb) * scale;
                        atomicAdd(&out[((b * C_INC + c) * T_LEN + (t0 + ml)) * F_BINS + f], val);
                    }
                }
            }
        }
    }
}

__global__ void bandsplit_naive(const float* __restrict__ x,
                                const float* __restrict__ pre_w,
                                const float* __restrict__ pre_b,
                                const float* __restrict__ post_w,
                                const float* __restrict__ post_b,
                                const float* __restrict__ mel,
                                const float* __restrict__ mask,
                                const float* __restrict__ ola,
                                const int*   __restrict__ idx,
                                float* __restrict__ out,
                                int W)
{
    const int i1 = 2 * W;
    extern __shared__ float sh[];
    float* g = sh;
    float* z = sh + i1;
    const int m = blockIdx.x, k = blockIdx.y;
    const int b = m / T_LEN, t = m % T_LEN;
    const int tid = threadIdx.x;
    for (int j = tid; j < i1; j += 128) {
        int w = j >> 1, c = j & 1;
        int f = idx[k * W + w];
        g[j] = x[((b * C_INC + c) * T_LEN + t) * F_BINS + f] * mel[k * W + w] * mask[k * W + w];
    }
    __syncthreads();
    {
        int d = tid;
        float a = pre_b[k * D_OUTC + d];
        for (int i = 0; i < i1; ++i) a += g[i] * pre_w[(k * i1 + i) * D_OUTC + d];
        z[d] = a;
    }
    __syncthreads();
    for (int o = tid; o < i1; o += 128) {
        int w = o >> 1, c = o & 1;
        float mk = mask[k * W + w];
        if (mk == 0.f) continue;
        float a = post_b[k * i1 + o];
        for (int d = 0; d < D_OUTC; ++d) a += z[d] * post_w[(k * D_OUTC + d) * i1 + o];
        int f = idx[k * W + w];
        atomicAdd(&out[((b * C_INC + c) * T_LEN + t) * F_BINS + f], a * mk / ola[f]);
    }
}

extern "C" void kernel_launch(void* const* d_in, const int* in_sizes, int n_in,
                              void* d_out, int out_size, void* d_ws, size_t ws_size,
                              hipStream_t stream) {
    const float* x      = (const float*)d_in[0];
    const float* pre_w  = (const float*)d_in[1];
    const float* pre_b  = (const float*)d_in[2];
    const float* post_w = (const float*)d_in[3];
    const float* post_b = (const float*)d_in[4];
    const float* mel    = (const float*)d_in[5];
    const float* mask   = (const float*)d_in[6];
    const float* ola    = (const float*)d_in[7];
    const int*   idxp   = (const int*)d_in[8];
    float* out = (float*)d_out;

    const int W  = in_sizes[8] / N_BANDS;
    const int i1 = 2 * W;
    const int Mrows = in_sizes[0] / (C_INC * F_BINS);
    const int K1PA = 2 * ((W + 15) & ~15);

    const size_t S1 = (size_t)N_BANDS * D_OUTC * K1PA;
    const size_t wbytes   = 4 * S1;                              // 2 arrays x 2B
    const size_t pbs_off  = (wbytes + 15) & ~(size_t)15;
    const size_t inv_off  = (pbs_off + (size_t)N_BANDS * i1 * 4 + 15) & ~(size_t)15;
    const size_t len_off  = inv_off + (size_t)F_BINS * 4 * 4;
    const size_t lenp_off = len_off + N_BANDS * 4;
    const size_t offt_off = lenp_off + N_BANDS * 4;
    const size_t strt_off = offt_off + (N_BANDS + 1) * 4;
    const size_t perm_off = strt_off + N_BANDS * 4;
    const size_t y_off    = (perm_off + N_BANDS * 4 + 255) & ~(size_t)255;
    const size_t need     = y_off + (size_t)Mrows * SCAP * sizeof(__half);

    if (W <= MAX_W && (Mrows % 64) == 0 && (Mrows % T_LEN) == 0 && ws_size >= need) {
        char* ws = (char*)d_ws;
        unsigned short* wB1h = (unsigned short*)ws;
        unsigned short* wB2h = wB1h + S1;
        float* postbS = (float*)(ws + pbs_off);
        int* inv   = (int*)(ws + inv_off);
        int* lenT  = (int*)(ws + len_off);
        int* lenPT = (int*)(ws + lenp_off);
        int* offT  = (int*)(ws + offt_off);
        int* startT= (int*)(ws + strt_off);
        int* permT = (int*)(ws + perm_off);
        __half* y  = (__half*)(ws + y_off);

        k_len<<<N_BANDS, 64, 0, stream>>>(mask, idxp, W, lenT, startT);
        k_scan<<<1, N_BANDS, 0, stream>>>(lenT, lenPT, offT, permT);
        dim3 g1(K1PA / 32, N_BANDS);
        prep_w1<<<g1, 256, 0, stream>>>(pre_w, mel, mask, lenPT, wB1h, W, i1, K1PA);
        prep_w2<<<g1, 256, 0, stream>>>(post_w, post_b, mask, idxp, ola, wB2h, postbS,
                                        W, i1, K1PA);
        k_inv2<<<(F_BINS + 255) / 256, 256, 0, stream>>>(startT, lenT, offT, inv);
        const int nmt = Mrows / 64;
        bandsplit_main<<<nmt * N_BANDS, 128, 0, stream>>>(x, wB1h, wB2h,
                                                 pre_b, postbS, lenT, lenPT, offT, startT,
                                                 permT, y, i1, K1PA, nmt);
        k_merge<<<4096, 256, 0, stream>>>(y, inv, out, Mrows);
        return;
    }

    hipMemsetAsync(d_out, 0, (size_t)out_size * sizeof(float), stream);
    if (W <= MAX_W && (Mrows % MT) == 0) {
        dim3 grid(Mrows / MT, N_BANDS);
        bandsplit_fused<<<grid, TPB, 0, stream>>>(x, pre_w, pre_b, post_w, post_b,
                                                  mel, mask, ola, idxp, out, W);
    } else {
        dim3 grid(Mrows, N_BANDS);
        size_t shmem = (size_t)(2 * W + D_OUTC) * sizeof(float);
        bandsplit_naive<<<grid, 128, shmem, stream>>>(x, pre_w, pre_b, post_w, post_b,
                                                      mel, mask, ola, idxp, out, W);
    }
}